// Round 1
// baseline (3057.848 us; speedup 1.0000x reference)
//
#include <hip/hip_runtime.h>

#define WAVE 64
#define THRESH 0.5f
#define MAXP 4096

// All-lanes argmin butterfly reduce over the wave, first-index tie-break
// (matches jnp.argmin): min value via xor-shuffles, then lowest lane holding it.
__device__ __forceinline__ void argminReduce64(float v, int idx, float& mv, int& mi) {
    float m = v;
#pragma unroll
    for (int off = 1; off < 64; off <<= 1)
        m = fminf(m, __shfl_xor(m, off, 64));
    unsigned long long b = __ballot(v == m);
    int lane = __ffsll(b) - 1;
    mv = m;
    mi = __shfl(idx, lane, 64);
}

// Single-wave sequential simulation of the scalar state (priorities + count).
// Records src[slot] = stream index of last write into that slot (-1 = untouched).
__global__ __launch_bounds__(64) void sim_kernel(
    const float* __restrict__ scores,
    const float* __restrict__ priorities,
    const int* __restrict__ countPtr,
    int N, int P,
    float* __restrict__ outPrior,
    float* __restrict__ outCnt,
    int* __restrict__ srcOut) {
    __shared__ float pr[MAXP];
    __shared__ int srcLds[MAXP];
    const int lane = threadIdx.x;
    const int NG = P >> 6;  // groups of 64

    for (int k = lane; k < P; k += WAVE) {
        pr[k] = priorities[k];
        srcLds[k] = -1;
    }
    __syncthreads();

    int cnt = *countPtr;
    float curMin = 0.0f;
    int curMinIdx = 0;
    float gv = __builtin_inff();  // per-lane: argmin value of group `lane`
    int gi = 0;                   // per-lane: argmin global index of group `lane`
    bool minsValid = false;

    for (int base = 0; base < N; base += WAVE) {
        float sc_l = (base + lane < N) ? scores[base + lane] : 0.0f;
        // valid = sc > THRESH (strict, like reference)
        unsigned long long mask = __ballot(sc_l > THRESH);
        while (mask) {
            int j = __ffsll(mask) - 1;
            mask &= mask - 1;
            float sc = __shfl(sc_l, j, 64);
            if (cnt < P) {
                // phase A: append at slot cnt (argmin irrelevant while has_room)
                if (lane == 0) { pr[cnt] = sc; srcLds[cnt] = base + j; }
                cnt++;
            } else {
                if (!minsValid) {
                    // rebuild all group argmins once at the fill->replace transition
                    gv = __builtin_inff();
                    gi = 0;
                    for (int g = 0; g < NG; ++g) {
                        int idx = (g << 6) | lane;
                        float v = pr[idx];
                        float m; int mi;
                        argminReduce64(v, idx, m, mi);
                        if (lane == g) { gv = m; gi = mi; }
                    }
                    argminReduce64(gv, gi, curMin, curMinIdx);
                    minsValid = true;
                    // prune items that can no longer write (min is non-decreasing)
                    mask &= __ballot(sc_l > curMin);
                }
                if (sc > curMin) {  // replace_ok, strict like reference
                    int widx = curMinIdx;
                    int g = widx >> 6;
                    if (lane == 0) { pr[widx] = sc; srcLds[widx] = base + j; }
                    // rescan group g; substitute the written value so we don't
                    // depend on the LDS store having landed
                    int idx = (g << 6) | lane;
                    float v = (idx == widx) ? sc : pr[idx];
                    float m; int mi;
                    argminReduce64(v, idx, m, mi);
                    if (lane == g) { gv = m; gi = mi; }
                    argminReduce64(gv, gi, curMin, curMinIdx);
                    mask &= __ballot(sc_l > curMin);
                }
            }
        }
    }

    __syncthreads();
    for (int k = lane; k < P; k += WAVE) {
        outPrior[k] = pr[k];
        srcOut[k] = srcLds[k];
    }
    if (lane == 0) outCnt[0] = (float)cnt;
}

// Fully parallel pool materialization: one block per slot row.
__global__ __launch_bounds__(256) void gather_kernel(
    const float* __restrict__ summaries,
    const float* __restrict__ pool,
    const int* __restrict__ src,
    float* __restrict__ outPool, int D) {
    int p = blockIdx.x;
    int s = src[p];
    const float* row = (s >= 0) ? (summaries + (size_t)s * D) : (pool + (size_t)p * D);
    float* o = outPool + (size_t)p * D;
    if ((D & 3) == 0) {
        for (int k = (threadIdx.x << 2); k < D; k += (blockDim.x << 2)) {
            float4 v = *(const float4*)(row + k);
            *(float4*)(o + k) = v;
        }
    } else {
        for (int k = threadIdx.x; k < D; k += blockDim.x) o[k] = row[k];
    }
}

extern "C" void kernel_launch(void* const* d_in, const int* in_sizes, int n_in,
                              void* d_out, int out_size, void* d_ws, size_t ws_size,
                              hipStream_t stream) {
    const float* summaries  = (const float*)d_in[0];
    const float* scores     = (const float*)d_in[1];
    const float* pool       = (const float*)d_in[2];
    const float* priorities = (const float*)d_in[3];
    const int*   count      = (const int*)d_in[4];

    int N = in_sizes[1];            // 16384
    int P = in_sizes[3];            // 4096
    int D = in_sizes[0] / N;        // 1024

    float* outPool  = (float*)d_out;
    float* outPrior = outPool + (size_t)P * D;
    float* outCnt   = outPrior + P;
    int*   src      = (int*)d_ws;   // P ints of scratch

    sim_kernel<<<1, 64, 0, stream>>>(scores, priorities, count, N, P,
                                     outPrior, outCnt, src);
    gather_kernel<<<P, 256, 0, stream>>>(summaries, pool, src, outPool, D);
}

// Round 2
// 1573.005 us; speedup vs baseline: 1.9440x; 1.9440x over previous
//
#include <hip/hip_runtime.h>

typedef unsigned long long u64;
#define THRESH 0.5f
#define ALL1 0xFFFFFFFFFFFFFFFFull

__device__ __forceinline__ u64 shflU64(u64 v, int src) { return __shfl(v, src, 64); }
__device__ __forceinline__ u64 shflxU64(u64 v, int m) { return __shfl_xor(v, m, 64); }
__device__ __forceinline__ float keyVal(u64 k) { return __uint_as_float((unsigned)(k >> 32)); }
__device__ __forceinline__ u64 packKey(float v, int slot) {
    return ((u64)__float_as_uint(v) << 32) | (unsigned)slot;
}
__device__ __forceinline__ float waveMinF(float v) {
#pragma unroll
    for (int off = 1; off < 64; off <<= 1) v = fminf(v, __shfl_xor(v, off, 64));
    return v;
}
__device__ __forceinline__ float waveMaxF(float v) {
#pragma unroll
    for (int off = 1; off < 64; off <<= 1) v = fmaxf(v, __shfl_xor(v, off, 64));
    return v;
}

// Full bitonic sort of 64 keys (one per lane), ascending across lanes.
__device__ __forceinline__ void sort64(u64 &key, int lane) {
#pragma unroll
    for (int k = 2; k <= 64; k <<= 1) {
#pragma unroll
        for (int j = k >> 1; j > 0; j >>= 1) {
            u64 p = shflxU64(key, j);
            bool takeMax = ((lane & j) != 0) != ((lane & k) != 0);
            u64 mn = key < p ? key : p;
            u64 mx = key < p ? p : key;
            key = takeMax ? mx : mn;
        }
    }
}
// Sort a bitonic sequence ascending.
__device__ __forceinline__ void bitonicMerge64(u64 &key, int lane) {
#pragma unroll
    for (int j = 32; j > 0; j >>= 1) {
        u64 p = shflxU64(key, j);
        u64 mn = key < p ? key : p;
        u64 mx = key < p ? p : key;
        key = ((lane & j) != 0) ? mx : mn;
    }
}

// Rebuild B = exact bottom-64 of pool (by (value,slot) key), sorted ascending.
// pivot = max over lanes of per-lane min guarantees >= 64 candidates.
__device__ void rebuildB(const float* pr, u64* cand, int lane, int P,
                         u64 &B, int &m, float &curMinVal) {
    const u64 laneLt = (1ull << lane) - 1;
    float vmin = __builtin_inff();
    for (int c = 0; c < P; c += 64) vmin = fminf(vmin, pr[c + lane]);
    float tau = waveMaxF(vmin);
    int nc = 0;
    for (int c = 0; c < P; c += 64) {
        int slot = c + lane;
        float v = pr[slot];
        bool pred = (v <= tau);
        u64 b = __ballot(pred);
        if (pred) cand[nc + (int)__popcll(b & laneLt)] = packKey(v, slot);
        nc += (int)__popcll(b);
    }
    u64 Bn = (lane < nc) ? cand[lane] : ALL1;
    sort64(Bn, lane);
    for (int g = 64; g < nc; g += 64) {
        u64 kk = (g + lane < nc) ? cand[g + lane] : ALL1;
        sort64(kk, lane);
        u64 rev = shflU64(kk, 63 - lane);      // descending copy
        u64 M = Bn < rev ? Bn : rev;           // 64 smallest of union, bitonic
        bitonicMerge64(M, lane);
        Bn = M;
    }
    B = Bn;
    m = (nc < 64) ? nc : 64;
    curMinVal = keyVal(shflU64(B, 0));
}

__global__ __launch_bounds__(64) void sim_kernel(
    const float* __restrict__ scores,
    const float* __restrict__ priorities,
    const int* __restrict__ countPtr,
    int N, int P,
    float* __restrict__ outPrior,
    float* __restrict__ outCnt,
    int* __restrict__ srcOut)
{
    __shared__ float pr[4096];
    __shared__ int srcLds[4096];
    __shared__ u64 cand[4096];
    const int lane = threadIdx.x;
    const u64 laneBit = 1ull << lane;
    const u64 laneLt = laneBit - 1;

    for (int k = lane; k < P; k += 64) { pr[k] = priorities[k]; srcLds[k] = -1; }
    __syncthreads();

    int cnt = *countPtr;
    u64 B = ALL1;            // sorted eviction buffer: exact bottom-m of pool
    int m = 0;
    bool built = false;
    float curMinVal = 0.f;

    float sc_l = (lane < N) ? scores[lane] : 0.f;
    for (int base = 0; base < N; base += 64) {
        float sc = sc_l;
        if (base + 64 < N) sc_l = scores[base + 64 + lane];  // prefetch next chunk
        u64 mask = __ballot(sc > THRESH);
        if (!mask) continue;

        if (cnt < P) {
            // Batched append (handles the transition chunk too): the first
            // nApp valid lanes (in lane==stream order) take slots cnt..cnt+nApp-1.
            int k = (int)__popcll(mask);
            int nApp = P - cnt; if (nApp > k) nApp = k;
            bool val_l = (mask & laneBit) != 0;
            int pos = (int)__popcll(mask & laneLt);
            bool doApp = val_l && (pos < nApp);
            if (doApp) { pr[cnt + pos] = sc; srcLds[cnt + pos] = base + lane; }
            u64 appMask = __ballot(doApp);
            mask &= ~appMask;
            cnt += nApp;
        }
        if (!mask) continue;

        // Replacement phase (pool full from here on).
        if (!built) { rebuildB(pr, cand, lane, P, B, m, curMinVal); built = true; }
        mask &= __ballot(sc > curMinVal);
        while (mask) {
            int k = (int)__popcll(mask);
            if (m < k) rebuildB(pr, cand, lane, P, B, m, curMinVal);
            float msc = waveMinF((mask & laneBit) ? sc : __builtin_inff());
            float bkv = keyVal(shflU64(B, k - 1));
            if (msc > bkv) {
                // FAST PATH: all k inserters strictly above B[k-1] -> the k
                // evictions are exactly B[0..k-1] in rank order; do them all
                // in parallel.
                bool ins = (mask & laneBit) != 0;
                int r = (int)__popcll(mask & laneLt);
                u64 be = shflU64(B, ins ? r : 0);
                int slot = (int)(be & 0xFFFFFFFFull);
                if (ins) { pr[slot] = sc; srcLds[slot] = base + lane; }
                u64 mykey = packKey(sc, slot);
                u64 shifted = shflU64(B, (lane + k) & 63);
                B = (lane + k < 64) ? shifted : ALL1;
                m -= k;
                if (m == 0) {
                    rebuildB(pr, cand, lane, P, B, m, curMinVal);
                } else {
                    // stragglers: inserted values that belong inside the buffer
                    u64 bmax = shflU64(B, m - 1);
                    u64 smask = __ballot(ins && (mykey < bmax));
                    while (smask) {
                        int j = __ffsll(smask) - 1; smask &= smask - 1;
                        u64 kk = shflU64(mykey, j);
                        u64 bb = __ballot(B < kk);
                        int p = (int)__popcll(bb);
                        if (p < m) {  // belongs inside exact-bottom-m coverage
                            u64 up = shflU64(B, (lane + 63) & 63);
                            B = (lane < p) ? B : (lane == p ? kk : up);
                            if (m < 64) m++;
                        }
                    }
                    curMinVal = keyVal(shflU64(B, 0));
                }
                mask = 0;
            } else {
                // SERIAL: one item — evict B[0], maybe insert into buffer.
                int j = __ffsll(mask) - 1; mask &= mask - 1;
                float scj = __shfl(sc, j, 64);
                if (scj > curMinVal) {
                    u64 b0 = shflU64(B, 0);
                    int widx = (int)(b0 & 0xFFFFFFFFull);
                    if (lane == 0) { pr[widx] = scj; srcLds[widx] = base + j; }
                    u64 key = packKey(scj, widx);
                    u64 bb = __ballot(B < key);
                    int p = (int)__popcll(bb);          // >= 1 (B[0] < key)
                    u64 up = shflU64(B, (lane + 1) & 63);
                    if (p < m) {
                        // remove B[0], insert key at p-1: coverage stays exact
                        B = (lane < p - 1) ? up : (lane == p - 1 ? key : B);
                    } else {
                        // key beyond coverage: just remove B[0]
                        B = (lane < m - 1) ? up : ALL1;
                        m--;
                    }
                    if (m == 0) rebuildB(pr, cand, lane, P, B, m, curMinVal);
                    else curMinVal = keyVal(shflU64(B, 0));
                    mask &= __ballot(sc > curMinVal);
                }
            }
        }
    }

    __syncthreads();
    for (int k = lane; k < P; k += 64) { outPrior[k] = pr[k]; srcOut[k] = srcLds[k]; }
    if (lane == 0) outCnt[0] = (float)cnt;
}

// Fully parallel pool materialization: one block per slot row.
__global__ __launch_bounds__(256) void gather_kernel(
    const float* __restrict__ summaries,
    const float* __restrict__ pool,
    const int* __restrict__ src,
    float* __restrict__ outPool, int D) {
    int p = blockIdx.x;
    int s = src[p];
    const float* row = (s >= 0) ? (summaries + (size_t)s * D) : (pool + (size_t)p * D);
    float* o = outPool + (size_t)p * D;
    if ((D & 3) == 0) {
        for (int k = (threadIdx.x << 2); k < D; k += (blockDim.x << 2)) {
            float4 v = *(const float4*)(row + k);
            *(float4*)(o + k) = v;
        }
    } else {
        for (int k = threadIdx.x; k < D; k += blockDim.x) o[k] = row[k];
    }
}

extern "C" void kernel_launch(void* const* d_in, const int* in_sizes, int n_in,
                              void* d_out, int out_size, void* d_ws, size_t ws_size,
                              hipStream_t stream) {
    const float* summaries  = (const float*)d_in[0];
    const float* scores     = (const float*)d_in[1];
    const float* pool       = (const float*)d_in[2];
    const float* priorities = (const float*)d_in[3];
    const int*   count      = (const int*)d_in[4];

    int N = in_sizes[1];            // 16384
    int P = in_sizes[3];            // 4096
    int D = in_sizes[0] / N;        // 1024

    float* outPool  = (float*)d_out;
    float* outPrior = outPool + (size_t)P * D;
    float* outCnt   = outPrior + P;
    int*   src      = (int*)d_ws;   // P ints of scratch

    sim_kernel<<<1, 64, 0, stream>>>(scores, priorities, count, N, P,
                                     outPrior, outCnt, src);
    gather_kernel<<<P, 256, 0, stream>>>(summaries, pool, src, outPool, D);
}

// Round 3
// 969.872 us; speedup vs baseline: 3.1528x; 1.6219x over previous
//
#include <hip/hip_runtime.h>

typedef unsigned long long u64;
#define THRESH 0.5f
#define ALL1 0xFFFFFFFFFFFFFFFFull

__device__ __forceinline__ u64 shflU64(u64 v, int src) { return __shfl(v, src, 64); }
__device__ __forceinline__ u64 shflxU64(u64 v, int m) { return __shfl_xor(v, m, 64); }
__device__ __forceinline__ float keyVal(u64 k) { return __uint_as_float((unsigned)(k >> 32)); }
__device__ __forceinline__ u64 packKey(float v, int slot) {
    return ((u64)__float_as_uint(v) << 32) | (unsigned)slot;
}
__device__ __forceinline__ float waveMinF(float v) {
#pragma unroll
    for (int off = 1; off < 64; off <<= 1) v = fminf(v, __shfl_xor(v, off, 64));
    return v;
}
__device__ __forceinline__ float waveMaxF(float v) {
#pragma unroll
    for (int off = 1; off < 64; off <<= 1) v = fmaxf(v, __shfl_xor(v, off, 64));
    return v;
}
__device__ __forceinline__ int waveSumI(int v) {
#pragma unroll
    for (int off = 1; off < 64; off <<= 1) v += __shfl_xor(v, off, 64);
    return v;
}

// Full bitonic sort of 64 keys (one per lane), ascending across lanes.
__device__ __forceinline__ void sort64(u64 &key, int lane) {
#pragma unroll
    for (int k = 2; k <= 64; k <<= 1) {
#pragma unroll
        for (int j = k >> 1; j > 0; j >>= 1) {
            u64 p = shflxU64(key, j);
            bool takeMax = ((lane & j) != 0) != ((lane & k) != 0);
            u64 mn = key < p ? key : p;
            u64 mx = key < p ? p : key;
            key = takeMax ? mx : mn;
        }
    }
}
// Sort a bitonic sequence ascending.
__device__ __forceinline__ void bitonicMerge64(u64 &key, int lane) {
#pragma unroll
    for (int j = 32; j > 0; j >>= 1) {
        u64 p = shflxU64(key, j);
        u64 mn = key < p ? key : p;
        u64 mx = key < p ? p : key;
        key = ((lane & j) != 0) ? mx : mn;
    }
}

// Rebuild B = exact bottom-64 of pool, sorted ascending by (value,slot) key.
// Single register-resident LDS pass; bisection-refined pivot; no per-iter ballots.
__device__ void rebuildB(const float* pr, u64* cand, int lane,
                         u64 &B, int &m, float &curMinVal) {
    // 1) pool -> registers: lane holds slots 256*i + 4*lane .. +3, i=0..15
    float4 v[16];
#pragma unroll
    for (int i = 0; i < 16; ++i) v[i] = ((const float4*)pr)[(i << 6) + lane];

    // 2) pivot: per-lane min -> tau = waveMax guarantees >= 64 candidates
    float mn = v[0].x;
#pragma unroll
    for (int i = 0; i < 16; ++i)
        mn = fminf(mn, fminf(fminf(v[i].x, v[i].y), fminf(v[i].z, v[i].w)));
    float lo = waveMinF(mn);
    float hi = waveMaxF(mn);

    int c = 0;
#pragma unroll
    for (int i = 0; i < 16; ++i)
        c += (v[i].x <= hi) + (v[i].y <= hi) + (v[i].z <= hi) + (v[i].w <= hi);
    int cHi = waveSumI(c);

    // 3) bisect hi down toward count in [64,128] (invariant: count(<=hi) >= 64)
    for (int it = 0; it < 5; ++it) {
        if (cHi <= 128 || !(lo < hi)) break;
        float mid = 0.5f * (lo + hi);
        if (!(mid > lo) || !(mid < hi)) break;
        int cc = 0;
#pragma unroll
        for (int i = 0; i < 16; ++i)
            cc += (v[i].x <= mid) + (v[i].y <= mid) + (v[i].z <= mid) + (v[i].w <= mid);
        cc = waveSumI(cc);
        if (cc >= 64) { hi = mid; cHi = cc; } else lo = mid;
    }

    // 4) per-lane count + exclusive wave prefix -> scatter candidates from regs
    int myc = 0;
#pragma unroll
    for (int i = 0; i < 16; ++i)
        myc += (v[i].x <= hi) + (v[i].y <= hi) + (v[i].z <= hi) + (v[i].w <= hi);
    int off = myc;
#pragma unroll
    for (int o = 1; o < 64; o <<= 1) {
        int y = __shfl_up(off, o, 64);
        if (lane >= o) off += y;
    }
    int nc = __shfl(off, 63, 64);
    off -= myc;  // exclusive prefix
#pragma unroll
    for (int i = 0; i < 16; ++i) {
        int slot = (i << 8) + (lane << 2);
        float x;
        x = v[i].x; if (x <= hi) cand[off++] = packKey(x, slot);
        x = v[i].y; if (x <= hi) cand[off++] = packKey(x, slot + 1);
        x = v[i].z; if (x <= hi) cand[off++] = packKey(x, slot + 2);
        x = v[i].w; if (x <= hi) cand[off++] = packKey(x, slot + 3);
    }

    // 5) bottom-64 of candidates via sort64 + reverse-merge
    u64 Bn = (lane < nc) ? cand[lane] : ALL1;
    sort64(Bn, lane);
    for (int g = 64; g < nc; g += 64) {
        u64 kk = (g + lane < nc) ? cand[g + lane] : ALL1;
        sort64(kk, lane);
        u64 rev = shflU64(kk, 63 - lane);   // descending copy
        u64 M = Bn < rev ? Bn : rev;        // 64 smallest of union (bitonic)
        bitonicMerge64(M, lane);
        Bn = M;
    }
    B = Bn;
    m = (nc < 64) ? nc : 64;
    curMinVal = keyVal(shflU64(B, 0));
}

__global__ __launch_bounds__(64, 1) void sim_kernel(
    const float* __restrict__ scores,
    const float* __restrict__ priorities,
    const int* __restrict__ countPtr,
    int N, int P,
    float* __restrict__ outPrior,
    float* __restrict__ outCnt,
    int* __restrict__ srcOut)
{
    __shared__ __align__(16) float pr[4096];
    __shared__ int srcLds[4096];
    __shared__ u64 cand[4096];
    const int lane = threadIdx.x;
    const u64 laneBit = 1ull << lane;
    const u64 laneLt = laneBit - 1;

    for (int k = lane; k < P; k += 64) { pr[k] = priorities[k]; srcLds[k] = -1; }
    __syncthreads();

    int cnt = *countPtr;
    u64 B = ALL1;                        // sorted eviction buffer (bottom-m of pool)
    int m = 0;
    float curMinVal = -__builtin_inff(); // safe (stale) lower bound of pool min

    float sc_l = (lane < N) ? scores[lane] : 0.f;
    for (int base = 0; base < N; base += 64) {
        float sc = sc_l;
        if (base + 64 + lane < N) sc_l = scores[base + 64 + lane];  // prefetch
        u64 mask = __ballot(sc > THRESH);
        if (!mask) continue;

        if (cnt < P) {
            // batched append: first nApp valid lanes take slots cnt..cnt+nApp-1
            int k = (int)__popcll(mask);
            int nApp = P - cnt; if (nApp > k) nApp = k;
            bool val_l = (mask & laneBit) != 0;
            int pos = (int)__popcll(mask & laneLt);
            bool doApp = val_l && (pos < nApp);
            if (doApp) { pr[cnt + pos] = sc; srcLds[cnt + pos] = base + lane; }
            mask &= ~__ballot(doApp);
            cnt += nApp;
            if (!mask) continue;
        }

        // replacement phase (pool full)
        mask &= __ballot(sc > curMinVal);
        while (mask) {
            int k = (int)__popcll(mask);
            if (m < k) {
                rebuildB(pr, cand, lane, B, m, curMinVal);
                mask &= __ballot(sc > curMinVal);
                if (!mask) break;
                k = (int)__popcll(mask);
            }
            float msc = waveMinF((mask & laneBit) ? sc : __builtin_inff());
            float bkv = keyVal(shflU64(B, k - 1));
            if (msc > bkv) {
                // FAST PATH: all k inserters strictly above B[k-1] -> they evict
                // B[0..k-1] in rank order, all in parallel.
                bool ins = (mask & laneBit) != 0;
                int r = (int)__popcll(mask & laneLt);
                u64 be = shflU64(B, ins ? r : 0);
                int slot = (int)(be & 0xFFFFFFFFull);
                if (ins) { pr[slot] = sc; srcLds[slot] = base + lane; }
                u64 mykey = packKey(sc, slot);
                u64 shifted = shflU64(B, (lane + k) & 63);
                B = (lane + k < 64) ? shifted : ALL1;
                m -= k;
                if (m > 0) {
                    // stragglers: inserted keys that belong inside coverage
                    u64 bmax = shflU64(B, m - 1);
                    u64 smask = __ballot(ins && (mykey < bmax));
                    while (smask) {
                        int j = __ffsll(smask) - 1; smask &= smask - 1;
                        u64 kk = shflU64(mykey, j);
                        u64 bb = __ballot(B < kk);
                        int p = (int)__popcll(bb);
                        if (p < m) {
                            u64 up = shflU64(B, (lane + 63) & 63);
                            B = (lane < p) ? B : (lane == p ? kk : up);
                            if (m < 64) m++;
                        }
                    }
                    curMinVal = keyVal(shflU64(B, 0));
                }
                // m==0: leave curMinVal stale (safe); loop-top rebuild next time
                mask = 0;
            } else {
                // SERIAL: one item — evict B[0], maybe insert into buffer.
                int j = __ffsll(mask) - 1; mask &= mask - 1;
                float scj = __shfl(sc, j, 64);
                if (scj > curMinVal) {
                    u64 b0 = shflU64(B, 0);
                    int widx = (int)(b0 & 0xFFFFFFFFull);
                    if (lane == 0) { pr[widx] = scj; srcLds[widx] = base + j; }
                    u64 key = packKey(scj, widx);
                    u64 bb = __ballot(B < key);
                    int p = (int)__popcll(bb);          // >= 1 since B[0] < key
                    u64 up = shflU64(B, (lane + 1) & 63);
                    if (p < m) {
                        // remove B[0], insert key at p-1: coverage stays exact
                        B = (lane < p - 1) ? up : (lane == p - 1 ? key : B);
                    } else {
                        B = (lane < m - 1) ? up : ALL1;
                        m--;
                    }
                    if (m > 0) curMinVal = keyVal(shflU64(B, 0));
                    // m==0: stale curMinVal is safe; loop-top rebuilds
                    mask &= __ballot(sc > curMinVal);
                }
            }
        }
    }

    __syncthreads();
    for (int k = lane; k < P; k += 64) { outPrior[k] = pr[k]; srcOut[k] = srcLds[k]; }
    if (lane == 0) outCnt[0] = (float)cnt;
}

// Fully parallel pool materialization: one block per slot row.
__global__ __launch_bounds__(256) void gather_kernel(
    const float* __restrict__ summaries,
    const float* __restrict__ pool,
    const int* __restrict__ src,
    float* __restrict__ outPool, int D) {
    int p = blockIdx.x;
    int s = src[p];
    const float* row = (s >= 0) ? (summaries + (size_t)s * D) : (pool + (size_t)p * D);
    float* o = outPool + (size_t)p * D;
    if ((D & 3) == 0) {
        for (int k = (threadIdx.x << 2); k < D; k += (blockDim.x << 2)) {
            float4 v = *(const float4*)(row + k);
            *(float4*)(o + k) = v;
        }
    } else {
        for (int k = threadIdx.x; k < D; k += blockDim.x) o[k] = row[k];
    }
}

extern "C" void kernel_launch(void* const* d_in, const int* in_sizes, int n_in,
                              void* d_out, int out_size, void* d_ws, size_t ws_size,
                              hipStream_t stream) {
    const float* summaries  = (const float*)d_in[0];
    const float* scores     = (const float*)d_in[1];
    const float* pool       = (const float*)d_in[2];
    const float* priorities = (const float*)d_in[3];
    const int*   count      = (const int*)d_in[4];

    int N = in_sizes[1];            // 16384
    int P = in_sizes[3];            // 4096
    int D = in_sizes[0] / N;        // 1024

    float* outPool  = (float*)d_out;
    float* outPrior = outPool + (size_t)P * D;
    float* outCnt   = outPrior + P;
    int*   src      = (int*)d_ws;   // P ints of scratch

    sim_kernel<<<1, 64, 0, stream>>>(scores, priorities, count, N, P,
                                     outPrior, outCnt, src);
    gather_kernel<<<P, 256, 0, stream>>>(summaries, pool, src, outPool, D);
}